// Round 1
// 546.243 us; speedup vs baseline: 1.0375x; 1.0375x over previous
//
#include <hip/hip_runtime.h>

typedef __attribute__((ext_vector_type(8))) short short8;
typedef __attribute__((ext_vector_type(4))) float f32x4;

#define B_    8
#define T_    1024
#define C_    2048
#define H_    16
#define HKV_  4
#define HD_   128
#define M_    8192
#define NQKV_ 3072
#define KDIM_ 2048

__device__ __forceinline__ unsigned short f2bf(float f) {
  unsigned u = __float_as_uint(f);
  u += 0x7FFF + ((u >> 16) & 1);
  return (unsigned short)(u >> 16);
}
__device__ __forceinline__ float bf2f(unsigned short h) {
  return __uint_as_float(((unsigned)h) << 16);
}

__device__ __forceinline__ void async16(const unsigned short* g, unsigned short* l) {
  __builtin_amdgcn_global_load_lds(
      (const unsigned int __attribute__((address_space(1)))*)g,
      (unsigned int __attribute__((address_space(3)))*)l,
      16, 0, 0);
}

// ---------------- fp32 -> bf16 straight convert (x) ----------------
__global__ __launch_bounds__(256) void cvt_bf16_kernel(const float* __restrict__ in,
                                                       unsigned short* __restrict__ out) {
  int idx = blockIdx.x * 256 + threadIdx.x;
  float4 v = ((const float4*)in)[idx];
  ushort4 o;
  o.x = f2bf(v.x); o.y = f2bf(v.y); o.z = f2bf(v.z); o.w = f2bf(v.w);
  ((ushort4*)out)[idx] = o;
}

// ------- fp32 [R][Cc] -> bf16 transposed out[c*ldo + r] (weights) -------
__global__ __launch_bounds__(256) void tpose_f32_bf16(const float* __restrict__ in,
                                                      unsigned short* __restrict__ out,
                                                      int Cc, int ldo) {
  __shared__ unsigned short tile[32][33];
  int c0 = blockIdx.x * 32, r0 = blockIdx.y * 32;
  int tx = threadIdx.x, ty = threadIdx.y;
#pragma unroll
  for (int j = 0; j < 4; j++)
    tile[ty + j * 8][tx] = f2bf(in[(size_t)(r0 + ty + j * 8) * Cc + c0 + tx]);
  __syncthreads();
#pragma unroll
  for (int j = 0; j < 4; j++)
    out[(size_t)(c0 + ty + j * 8) * ldo + r0 + tx] = tile[tx][ty + j * 8];
}

// ------- bf16 V-part of qkv -> vT[b][c][t] (per-batch transpose) -------
__global__ __launch_bounds__(256) void vtpose(const unsigned short* __restrict__ qkv,
                                              unsigned short* __restrict__ vt) {
  __shared__ unsigned short tile[32][33];
  int b = blockIdx.z;
  int c0 = blockIdx.x * 32, t0 = blockIdx.y * 32;
  int tx = threadIdx.x, ty = threadIdx.y;
  const unsigned short* src = qkv + (size_t)b * T_ * NQKV_ + 2560;
#pragma unroll
  for (int j = 0; j < 4; j++)
    tile[ty + j * 8][tx] = src[(size_t)(t0 + ty + j * 8) * NQKV_ + c0 + tx];
  __syncthreads();
  unsigned short* dst = vt + (size_t)b * 512 * T_;
#pragma unroll
  for (int j = 0; j < 4; j++)
    dst[(size_t)(c0 + ty + j * 8) * T_ + t0 + tx] = tile[tx][ty + j * 8];
}

// ------- RoPE + relayout: qkv[m][3072] -> qatt[b][h][t][d], katt[b][kh][t][d] -------
__global__ __launch_bounds__(256) void rope_kernel(const unsigned short* __restrict__ qkv,
                                                   const float* __restrict__ sinp,
                                                   const float* __restrict__ cosp,
                                                   unsigned short* __restrict__ qatt,
                                                   unsigned short* __restrict__ katt) {
  int m = blockIdx.x;
  int b = m >> 10, t = m & 1023;
  int tid = threadIdx.x;
  int d = tid & 63;
  const unsigned short* row = qkv + (size_t)m * NQKV_;
  float c0 = cosp[t * 128 + d], s0 = sinp[t * 128 + d];
  float c1 = cosp[t * 128 + d + 64], s1 = sinp[t * 128 + d + 64];
#pragma unroll
  for (int h0 = 0; h0 < 16; h0 += 4) {
    int h = h0 + (tid >> 6);
    float x0 = bf2f(row[h * 128 + d]);
    float x1 = bf2f(row[h * 128 + d + 64]);
    size_t o = ((size_t)(b * 16 + h) * 1024 + t) * 128 + d;
    qatt[o]      = f2bf(x0 * c0 - x1 * s0);
    qatt[o + 64] = f2bf(x1 * c1 + x0 * s1);
  }
  {
    int kh = tid >> 6;
    float x0 = bf2f(row[2048 + kh * 128 + d]);
    float x1 = bf2f(row[2048 + kh * 128 + d + 64]);
    size_t o = ((size_t)(b * 4 + kh) * 1024 + t) * 128 + d;
    katt[o]      = f2bf(x0 * c0 - x1 * s0);
    katt[o + 64] = f2bf(x1 * c1 + x0 * s1);
  }
}

// ------- m97-style GEMM: C[M x N] = A[M x K] * BT[N x K]^T, K=2048 -------
template <int OUTF32>
__global__ __launch_bounds__(256) void gemm_bf16(const unsigned short* __restrict__ A,
                                                 const unsigned short* __restrict__ BT,
                                                 void* __restrict__ Cout, int N) {
  __shared__ unsigned short lA[128 * 32];
  __shared__ unsigned short lB[128 * 32];
  const int K = KDIM_;
  int tid = threadIdx.x;
  int lane = tid & 63;
  int w = tid >> 6;
  int quad = lane >> 4, l16 = lane & 15;
  int bm = blockIdx.y, bn = blockIdx.x;
  const unsigned short* Ab = A + (size_t)bm * 128 * K;
  const unsigned short* Bb = BT + (size_t)bn * 128 * K;
  int i0 = tid, i1 = tid + 256;
  int ra0 = i0 >> 2, ca0 = (i0 & 3) * 8;
  int ra1 = i1 >> 2, ca1 = (i1 & 3) * 8;
  int wm = (w >> 1) * 64, wn = (w & 1) * 64;
  f32x4 acc[4][4] = {};
  for (int k0 = 0; k0 < K; k0 += 32) {
    __syncthreads();
    async16(Ab + (size_t)ra0 * K + k0 + ca0, &lA[i0 * 8]);
    async16(Ab + (size_t)ra1 * K + k0 + ca1, &lA[i1 * 8]);
    async16(Bb + (size_t)ra0 * K + k0 + ca0, &lB[i0 * 8]);
    async16(Bb + (size_t)ra1 * K + k0 + ca1, &lB[i1 * 8]);
    __syncthreads();
    short8 af[4], bfr[4];
#pragma unroll
    for (int mt = 0; mt < 4; mt++)
      af[mt] = *(const short8*)&lA[(wm + mt * 16 + l16) * 32 + quad * 8];
#pragma unroll
    for (int nt = 0; nt < 4; nt++)
      bfr[nt] = *(const short8*)&lB[(wn + nt * 16 + l16) * 32 + quad * 8];
#pragma unroll
    for (int mt = 0; mt < 4; mt++)
#pragma unroll
      for (int nt = 0; nt < 4; nt++)
        acc[mt][nt] = __builtin_amdgcn_mfma_f32_16x16x32_bf16(af[mt], bfr[nt], acc[mt][nt], 0, 0, 0);
  }
#pragma unroll
  for (int mt = 0; mt < 4; mt++) {
#pragma unroll
    for (int nt = 0; nt < 4; nt++) {
      int n = bn * 128 + wn + nt * 16 + l16;
#pragma unroll
      for (int r = 0; r < 4; r++) {
        int m = bm * 128 + wm + mt * 16 + quad * 4 + r;
        if (OUTF32)
          ((float*)Cout)[(size_t)m * N + n] = acc[mt][nt][r];
        else
          ((unsigned short*)Cout)[(size_t)m * N + n] = f2bf(acc[mt][nt][r]);
      }
    }
  }
}

// ------- flash attention v3: 4 waves/block, 128 q-rows (32/wave), XOR-swizzled LDS -------
// K tile [ks][row][tq] and V tile [ks2][d][tq] staged via global_load_lds with the
// 16B-granule XOR swizzle applied on the GLOBAL source address (tq ^= row&3); the
// fragment reads apply the same XOR (quad*8 ^ (l16&3)*8) -> 8-way bank conflicts
// become 2-way (free). Each wave owns 32 q-rows (2 m-tiles) so the K/V LDS read
// traffic per FLOP halves vs 16 rows/wave. P round-trips through the per-wave
// 16-row region in lK sequentially per m-tile (lgkmcnt(0)-protected reuse).
__global__ __launch_bounds__(256, 2) void attn_kernel(const unsigned short* __restrict__ Q,
                                                      const unsigned short* __restrict__ Km,
                                                      const unsigned short* __restrict__ Vt,
                                                      unsigned short* __restrict__ Y) {
  __shared__ __align__(16) unsigned short lK[8192];  // [ks 0..3][row 0..63][tq 0..3][8]
  __shared__ __align__(16) unsigned short lV[8192];  // [ks2 0..1][d 0..127][tq 0..3][8]
  int tid = threadIdx.x;
  int lane = tid & 63, w = tid >> 6;
  int quad = lane >> 4, l16 = lane & 15;
  int qt = 7 - blockIdx.x;  // heavy tiles dispatch first
  int bh = blockIdx.y;
  int b = bh >> 4, h = bh & 15, kh = h & 3;
  int qrow0 = qt * 128 + w * 32;
  const unsigned short* Qb = Q + ((size_t)bh * T_ + qrow0) * 128;
  const unsigned short* Kb = Km + (size_t)(b * 4 + kh) * T_ * 128;
  const unsigned short* Vb = Vt + (size_t)(b * 4 + kh) * 128 * T_;
  short8 qf[2][4];
#pragma unroll
  for (int mt = 0; mt < 2; mt++)
#pragma unroll
    for (int ks = 0; ks < 4; ks++)
      qf[mt][ks] = *(const short8*)&Qb[(mt * 16 + l16) * 128 + ks * 32 + quad * 8];
  f32x4 o[2][8] = {};
  float m_r[2][4], l_r[2][4];
#pragma unroll
  for (int mt = 0; mt < 2; mt++)
#pragma unroll
    for (int r = 0; r < 4; r++) {
      m_r[mt][r] = -1e30f;
      l_r[mt][r] = 0.f;
    }
  const float sc = 0.12751744690989f;  // log2(e)/sqrt(128)
  unsigned short* pb = &lK[w * 1152];  // per-wave 16-row P region, stride 72
  const int sw = (l16 & 3) * 8;        // read-side granule XOR (shorts)
  int ntile = 2 * qt + 2;
  for (int kt = 0; kt < ntile; kt++) {
    int n0 = kt * 64;
    __syncthreads();  // A: prior iter's lV/P reads done before restage
#pragma unroll
    for (int j = 0; j < 4; j++) {
      int i = tid + j * 256;  // K granule: ks=i>>8, row=(i>>2)&63, tq swizzled
      int tq = (i & 3) ^ ((i >> 2) & 3);
      async16(Kb + (size_t)(n0 + ((i >> 2) & 63)) * 128 + (i >> 8) * 32 + tq * 8,
              &lK[i * 8]);
    }
#pragma unroll
    for (int j = 0; j < 4; j++) {
      int i = tid + j * 256;  // V granule: ks2=i>>9, d=(i>>2)&127, tq swizzled
      int tq = (i & 3) ^ ((i >> 2) & 3);
      async16(Vb + (size_t)((i >> 2) & 127) * T_ + n0 + (i >> 9) * 32 + tq * 8,
              &lV[i * 8]);
    }
    __syncthreads();  // B: staging complete (vmcnt(0) drain)
    f32x4 s[2][4] = {};
#pragma unroll
    for (int ct = 0; ct < 4; ct++) {
      short8 kf[4];
#pragma unroll
      for (int ks = 0; ks < 4; ks++)
        kf[ks] = *(const short8*)&lK[ks * 2048 + (ct * 16 + l16) * 32 + (quad * 8 ^ sw)];
#pragma unroll
      for (int ks = 0; ks < 4; ks++) {
        s[0][ct] = __builtin_amdgcn_mfma_f32_16x16x32_bf16(qf[0][ks], kf[ks], s[0][ct], 0, 0, 0);
        s[1][ct] = __builtin_amdgcn_mfma_f32_16x16x32_bf16(qf[1][ks], kf[ks], s[1][ct], 0, 0, 0);
      }
    }
#pragma unroll
    for (int mt = 0; mt < 2; mt++)
#pragma unroll
      for (int ct = 0; ct < 4; ct++)
#pragma unroll
        for (int r = 0; r < 4; r++)
          s[mt][ct][r] *= sc;
    if (kt >= 2 * qt) {  // diagonal zone: causal mask
#pragma unroll
      for (int mt = 0; mt < 2; mt++)
#pragma unroll
        for (int ct = 0; ct < 4; ct++) {
          int n = n0 + ct * 16 + l16;
#pragma unroll
          for (int r = 0; r < 4; r++) {
            int q = qrow0 + mt * 16 + quad * 4 + r;
            if (n > q) s[mt][ct][r] = -1e30f;
          }
        }
    }
    float alpha[2][4];
#pragma unroll
    for (int mt = 0; mt < 2; mt++)
#pragma unroll
      for (int r = 0; r < 4; r++) {
        float v = fmaxf(fmaxf(s[mt][0][r], s[mt][1][r]), fmaxf(s[mt][2][r], s[mt][3][r]));
#pragma unroll
        for (int off = 1; off < 16; off <<= 1)
          v = fmaxf(v, __shfl_xor(v, off));
        float mn = fmaxf(m_r[mt][r], v);
        alpha[mt][r] = exp2f(m_r[mt][r] - mn);
        m_r[mt][r] = mn;
      }
#pragma unroll
    for (int mt = 0; mt < 2; mt++)
#pragma unroll
      for (int ct = 0; ct < 4; ct++)
#pragma unroll
        for (int r = 0; r < 4; r++)
          s[mt][ct][r] = exp2f(s[mt][ct][r] - m_r[mt][r]);
#pragma unroll
    for (int mt = 0; mt < 2; mt++)
#pragma unroll
      for (int r = 0; r < 4; r++) {
        float v = s[mt][0][r] + s[mt][1][r] + s[mt][2][r] + s[mt][3][r];
#pragma unroll
        for (int off = 1; off < 16; off <<= 1)
          v += __shfl_xor(v, off);
        l_r[mt][r] = l_r[mt][r] * alpha[mt][r] + v;
      }
#pragma unroll
    for (int mt = 0; mt < 2; mt++)
#pragma unroll
      for (int dt = 0; dt < 8; dt++)
#pragma unroll
        for (int r = 0; r < 4; r++)
          o[mt][dt][r] *= alpha[mt][r];
    __syncthreads();  // C: all waves' lK fragment reads done before P overwrite
    // ---- P m-tile 0 ----
#pragma unroll
    for (int ct = 0; ct < 4; ct++)
#pragma unroll
      for (int r = 0; r < 4; r++)
        pb[(quad * 4 + r) * 72 + ct * 16 + l16] = f2bf(s[0][ct][r]);
    __builtin_amdgcn_s_waitcnt(0xC07F);  // lgkmcnt(0): P0 writes visible
    short8 pa0[2];
#pragma unroll
    for (int ks2 = 0; ks2 < 2; ks2++)
      pa0[ks2] = *(const short8*)&pb[l16 * 72 + ks2 * 32 + quad * 8];
    __builtin_amdgcn_s_waitcnt(0xC07F);  // pa0 data returned before region reuse
    asm volatile("" ::: "memory");
    // ---- P m-tile 1 (same per-wave region, sequential reuse) ----
#pragma unroll
    for (int ct = 0; ct < 4; ct++)
#pragma unroll
      for (int r = 0; r < 4; r++)
        pb[(quad * 4 + r) * 72 + ct * 16 + l16] = f2bf(s[1][ct][r]);
    __builtin_amdgcn_s_waitcnt(0xC07F);  // lgkmcnt(0): P1 writes visible
    short8 pa1[2];
#pragma unroll
    for (int ks2 = 0; ks2 < 2; ks2++)
      pa1[ks2] = *(const short8*)&pb[l16 * 72 + ks2 * 32 + quad * 8];
    // ---- PV: V fragments read once, feed both m-tiles ----
#pragma unroll
    for (int dt = 0; dt < 8; dt++) {
#pragma unroll
      for (int ks2 = 0; ks2 < 2; ks2++) {
        short8 vf = *(const short8*)&lV[ks2 * 4096 + (dt * 16 + l16) * 32 + (quad * 8 ^ sw)];
        o[0][dt] = __builtin_amdgcn_mfma_f32_16x16x32_bf16(pa0[ks2], vf, o[0][dt], 0, 0, 0);
        o[1][dt] = __builtin_amdgcn_mfma_f32_16x16x32_bf16(pa1[ks2], vf, o[1][dt], 0, 0, 0);
      }
    }
  }
#pragma unroll
  for (int mt = 0; mt < 2; mt++)
#pragma unroll
    for (int r = 0; r < 4; r++) {
      int q = qrow0 + mt * 16 + quad * 4 + r;
      float inv = 1.f / l_r[mt][r];
      size_t base = ((size_t)(b * 1024 + q)) * 2048 + h * 128 + l16;
#pragma unroll
      for (int dt = 0; dt < 8; dt++)
        Y[base + dt * 16] = f2bf(o[mt][dt][r] * inv);
    }
}

extern "C" void kernel_launch(void* const* d_in, const int* in_sizes, int n_in,
                              void* d_out, int out_size, void* d_ws, size_t ws_size,
                              hipStream_t stream) {
  const float* x    = (const float*)d_in[0];
  const float* wq   = (const float*)d_in[1];
  const float* wk   = (const float*)d_in[2];
  const float* wv   = (const float*)d_in[3];
  const float* wo   = (const float*)d_in[4];
  const float* sinp = (const float*)d_in[5];
  const float* cosp = (const float*)d_in[6];

  char* ws = (char*)d_ws;
  unsigned short* WCATT = (unsigned short*)(ws);                 // [3072][2048] bf16
  unsigned short* WOT   = (unsigned short*)(ws + 12582912);      // [2048][2048] bf16
  unsigned short* XBF   = (unsigned short*)(ws + 20971520);      // [8192][2048] bf16
  unsigned short* QKV   = (unsigned short*)(ws + 54525952);      // [8192][3072] bf16
  unsigned short* KATT  = (unsigned short*)(ws + 104857600);     // [8*4][1024][128]
  unsigned short* VT    = (unsigned short*)(ws + 113246208);     // [8*4][128][1024]
  unsigned short* QATT  = XBF;  // alias: x_bf16 dead after GEMM1
  unsigned short* Y     = QKV;  // alias: qkv dead after rope+vtpose

  dim3 tb(32, 8);
  cvt_bf16_kernel<<<16384, 256, 0, stream>>>(x, XBF);
  tpose_f32_bf16<<<dim3(64, 64), tb, 0, stream>>>(wq, WCATT, 2048, 2048);
  tpose_f32_bf16<<<dim3(16, 64), tb, 0, stream>>>(wk, WCATT + (size_t)2048 * 2048, 512, 2048);
  tpose_f32_bf16<<<dim3(16, 64), tb, 0, stream>>>(wv, WCATT + (size_t)2560 * 2048, 512, 2048);
  tpose_f32_bf16<<<dim3(64, 64), tb, 0, stream>>>(wo, WOT, 2048, 2048);
  gemm_bf16<0><<<dim3(24, 64), 256, 0, stream>>>(XBF, WCATT, QKV, 3072);
  rope_kernel<<<8192, 256, 0, stream>>>(QKV, sinp, cosp, QATT, KATT);
  vtpose<<<dim3(16, 32, 8), tb, 0, stream>>>(QKV, VT);
  attn_kernel<<<dim3(8, 128), 256, 0, stream>>>(QATT, KATT, VT, Y);
  gemm_bf16<1><<<dim3(16, 64), 256, 0, stream>>>(Y, WOT, d_out, 2048);
}

// Round 3
// 527.615 us; speedup vs baseline: 1.0741x; 1.0353x over previous
//
#include <hip/hip_runtime.h>

typedef __attribute__((ext_vector_type(8))) short short8;
typedef __attribute__((ext_vector_type(4))) float f32x4;

#define B_    8
#define T_    1024
#define C_    2048
#define H_    16
#define HKV_  4
#define HD_   128
#define M_    8192
#define NQKV_ 3072
#define KDIM_ 2048

__device__ __forceinline__ unsigned short f2bf(float f) {
  unsigned u = __float_as_uint(f);
  u += 0x7FFF + ((u >> 16) & 1);
  return (unsigned short)(u >> 16);
}
__device__ __forceinline__ float bf2f(unsigned short h) {
  return __uint_as_float(((unsigned)h) << 16);
}

__device__ __forceinline__ void async16(const unsigned short* g, unsigned short* l) {
  __builtin_amdgcn_global_load_lds(
      (const unsigned int __attribute__((address_space(1)))*)g,
      (unsigned int __attribute__((address_space(3)))*)l,
      16, 0, 0);
}

// ---------------- fp32 -> bf16 straight convert (x) ----------------
__global__ __launch_bounds__(256) void cvt_bf16_kernel(const float* __restrict__ in,
                                                       unsigned short* __restrict__ out) {
  int idx = blockIdx.x * 256 + threadIdx.x;
  float4 v = ((const float4*)in)[idx];
  ushort4 o;
  o.x = f2bf(v.x); o.y = f2bf(v.y); o.z = f2bf(v.z); o.w = f2bf(v.w);
  ((ushort4*)out)[idx] = o;
}

// ------- fp32 [R][Cc] -> bf16 transposed out[c*ldo + r] (weights) -------
__global__ __launch_bounds__(256) void tpose_f32_bf16(const float* __restrict__ in,
                                                      unsigned short* __restrict__ out,
                                                      int Cc, int ldo) {
  __shared__ unsigned short tile[32][33];
  int c0 = blockIdx.x * 32, r0 = blockIdx.y * 32;
  int tx = threadIdx.x, ty = threadIdx.y;
#pragma unroll
  for (int j = 0; j < 4; j++)
    tile[ty + j * 8][tx] = f2bf(in[(size_t)(r0 + ty + j * 8) * Cc + c0 + tx]);
  __syncthreads();
#pragma unroll
  for (int j = 0; j < 4; j++)
    out[(size_t)(c0 + ty + j * 8) * ldo + r0 + tx] = tile[tx][ty + j * 8];
}

// ------- bf16 V-part of qkv -> vT[b][c][t] (per-batch transpose) -------
__global__ __launch_bounds__(256) void vtpose(const unsigned short* __restrict__ qkv,
                                              unsigned short* __restrict__ vt) {
  __shared__ unsigned short tile[32][33];
  int b = blockIdx.z;
  int c0 = blockIdx.x * 32, t0 = blockIdx.y * 32;
  int tx = threadIdx.x, ty = threadIdx.y;
  const unsigned short* src = qkv + (size_t)b * T_ * NQKV_ + 2560;
#pragma unroll
  for (int j = 0; j < 4; j++)
    tile[ty + j * 8][tx] = src[(size_t)(t0 + ty + j * 8) * NQKV_ + c0 + tx];
  __syncthreads();
  unsigned short* dst = vt + (size_t)b * 512 * T_;
#pragma unroll
  for (int j = 0; j < 4; j++)
    dst[(size_t)(c0 + ty + j * 8) * T_ + t0 + tx] = tile[tx][ty + j * 8];
}

// ------- RoPE + relayout: qkv[m][3072] -> qatt[b][h][t][d], katt[b][kh][t][d] -------
__global__ __launch_bounds__(256) void rope_kernel(const unsigned short* __restrict__ qkv,
                                                   const float* __restrict__ sinp,
                                                   const float* __restrict__ cosp,
                                                   unsigned short* __restrict__ qatt,
                                                   unsigned short* __restrict__ katt) {
  int m = blockIdx.x;
  int b = m >> 10, t = m & 1023;
  int tid = threadIdx.x;
  int d = tid & 63;
  const unsigned short* row = qkv + (size_t)m * NQKV_;
  float c0 = cosp[t * 128 + d], s0 = sinp[t * 128 + d];
  float c1 = cosp[t * 128 + d + 64], s1 = sinp[t * 128 + d + 64];
#pragma unroll
  for (int h0 = 0; h0 < 16; h0 += 4) {
    int h = h0 + (tid >> 6);
    float x0 = bf2f(row[h * 128 + d]);
    float x1 = bf2f(row[h * 128 + d + 64]);
    size_t o = ((size_t)(b * 16 + h) * 1024 + t) * 128 + d;
    qatt[o]      = f2bf(x0 * c0 - x1 * s0);
    qatt[o + 64] = f2bf(x1 * c1 + x0 * s1);
  }
  {
    int kh = tid >> 6;
    float x0 = bf2f(row[2048 + kh * 128 + d]);
    float x1 = bf2f(row[2048 + kh * 128 + d + 64]);
    size_t o = ((size_t)(b * 4 + kh) * 1024 + t) * 128 + d;
    katt[o]      = f2bf(x0 * c0 - x1 * s0);
    katt[o + 64] = f2bf(x1 * c1 + x0 * s1);
  }
}

// ------- m97-style GEMM: C[M x N] = A[M x K] * BT[N x K]^T, K=2048 -------
template <int OUTF32>
__global__ __launch_bounds__(256) void gemm_bf16(const unsigned short* __restrict__ A,
                                                 const unsigned short* __restrict__ BT,
                                                 void* __restrict__ Cout, int N) {
  __shared__ unsigned short lA[128 * 32];
  __shared__ unsigned short lB[128 * 32];
  const int K = KDIM_;
  int tid = threadIdx.x;
  int lane = tid & 63;
  int w = tid >> 6;
  int quad = lane >> 4, l16 = lane & 15;
  int bm = blockIdx.y, bn = blockIdx.x;
  const unsigned short* Ab = A + (size_t)bm * 128 * K;
  const unsigned short* Bb = BT + (size_t)bn * 128 * K;
  int i0 = tid, i1 = tid + 256;
  int ra0 = i0 >> 2, ca0 = (i0 & 3) * 8;
  int ra1 = i1 >> 2, ca1 = (i1 & 3) * 8;
  int wm = (w >> 1) * 64, wn = (w & 1) * 64;
  f32x4 acc[4][4] = {};
  for (int k0 = 0; k0 < K; k0 += 32) {
    __syncthreads();
    async16(Ab + (size_t)ra0 * K + k0 + ca0, &lA[i0 * 8]);
    async16(Ab + (size_t)ra1 * K + k0 + ca1, &lA[i1 * 8]);
    async16(Bb + (size_t)ra0 * K + k0 + ca0, &lB[i0 * 8]);
    async16(Bb + (size_t)ra1 * K + k0 + ca1, &lB[i1 * 8]);
    __syncthreads();
    short8 af[4], bfr[4];
#pragma unroll
    for (int mt = 0; mt < 4; mt++)
      af[mt] = *(const short8*)&lA[(wm + mt * 16 + l16) * 32 + quad * 8];
#pragma unroll
    for (int nt = 0; nt < 4; nt++)
      bfr[nt] = *(const short8*)&lB[(wn + nt * 16 + l16) * 32 + quad * 8];
#pragma unroll
    for (int mt = 0; mt < 4; mt++)
#pragma unroll
      for (int nt = 0; nt < 4; nt++)
        acc[mt][nt] = __builtin_amdgcn_mfma_f32_16x16x32_bf16(af[mt], bfr[nt], acc[mt][nt], 0, 0, 0);
  }
#pragma unroll
  for (int mt = 0; mt < 4; mt++) {
#pragma unroll
    for (int nt = 0; nt < 4; nt++) {
      int n = bn * 128 + wn + nt * 16 + l16;
#pragma unroll
      for (int r = 0; r < 4; r++) {
        int m = bm * 128 + wm + mt * 16 + quad * 4 + r;
        if (OUTF32)
          ((float*)Cout)[(size_t)m * N + n] = acc[mt][nt][r];
        else
          ((unsigned short*)Cout)[(size_t)m * N + n] = f2bf(acc[mt][nt][r]);
      }
    }
  }
}

// ------- flash attention v4: pipelined 2-phase staging, 1 barrier/tile -------
// Double-buffered lK/lV: tile t+1's global_load_lds issued BEFORE computing
// tile t, so HBM/L2 latency hides under QK+softmax+PV (T3 minimal 2-phase).
// P lives in its own LDS region lP (wave-private) -> no barrier between QK
// reads and P writes. Softmax: l-sum kept as per-lane partials (reduced once
// in epilogue; alpha is row-uniform so partials scale correctly); score scale
// folded into exp2 via fma. setprio(1) around MFMA clusters (T5).
// LDS = 72 KB -> 2 blocks/CU.
__global__ __launch_bounds__(256, 2) void attn_kernel(const unsigned short* __restrict__ Q,
                                                      const unsigned short* __restrict__ Km,
                                                      const unsigned short* __restrict__ Vt,
                                                      unsigned short* __restrict__ Y) {
  __shared__ __align__(16) unsigned short lK[2][8192];  // [buf][ks][row][tq][8]
  __shared__ __align__(16) unsigned short lV[2][8192];  // [buf][ks2][d][tq][8]
  __shared__ __align__(16) unsigned short lP[4608];     // [wave][16][72]
  int tid = threadIdx.x;
  int lane = tid & 63, w = tid >> 6;
  int quad = lane >> 4, l16 = lane & 15;
  int qt = 7 - blockIdx.x;  // heavy tiles dispatch first
  int bh = blockIdx.y;
  int b = bh >> 4, h = bh & 15, kh = h & 3;
  int qrow0 = qt * 128 + w * 32;
  const unsigned short* Qb = Q + ((size_t)bh * T_ + qrow0) * 128;
  const unsigned short* Kb = Km + (size_t)(b * 4 + kh) * T_ * 128;
  const unsigned short* Vb = Vt + (size_t)(b * 4 + kh) * 128 * T_;
  short8 qf[2][4];
#pragma unroll
  for (int mt = 0; mt < 2; mt++)
#pragma unroll
    for (int ks = 0; ks < 4; ks++)
      qf[mt][ks] = *(const short8*)&Qb[(mt * 16 + l16) * 128 + ks * 32 + quad * 8];
  f32x4 o[2][8] = {};
  float m_r[2][4], l_r[2][4];
#pragma unroll
  for (int mt = 0; mt < 2; mt++)
#pragma unroll
    for (int r = 0; r < 4; r++) {
      m_r[mt][r] = -1e30f;
      l_r[mt][r] = 0.f;
    }
  const float sc = 0.12751744690989f;  // log2(e)/sqrt(128)
  unsigned short* pb = &lP[w * 1152];  // per-wave 16-row P region, stride 72
  const int sw = (l16 & 3) * 8;        // read-side granule XOR (shorts)
  int ntile = 2 * qt + 2;

  // loop-invariant staging index parts (i = tid + j*256)
  int krow[4], kcol[4], vrow[4], vcol[4];
#pragma unroll
  for (int j = 0; j < 4; j++) {
    int i = tid + j * 256;
    int tq = (i & 3) ^ ((i >> 2) & 3);
    krow[j] = (i >> 2) & 63;
    kcol[j] = (i >> 8) * 32 + tq * 8;
    vrow[j] = (i >> 2) & 127;
    vcol[j] = (i >> 9) * 32 + tq * 8;
  }

  // prologue: stage tile 0 into buf 0
#pragma unroll
  for (int j = 0; j < 4; j++)
    async16(Kb + (size_t)krow[j] * 128 + kcol[j], &lK[0][(tid + j * 256) * 8]);
#pragma unroll
  for (int j = 0; j < 4; j++)
    async16(Vb + (size_t)vrow[j] * T_ + vcol[j], &lV[0][(tid + j * 256) * 8]);
  asm volatile("s_waitcnt vmcnt(0)" ::: "memory");
  __syncthreads();

  int cur = 0;
  for (int kt = 0; kt < ntile; kt++) {
    int n0 = kt * 64;
    // issue next tile's staging into the other buffer (latency hides under compute)
    if (kt + 1 < ntile) {
      int n1 = n0 + 64;
#pragma unroll
      for (int j = 0; j < 4; j++)
        async16(Kb + (size_t)(n1 + krow[j]) * 128 + kcol[j], &lK[cur ^ 1][(tid + j * 256) * 8]);
#pragma unroll
      for (int j = 0; j < 4; j++)
        async16(Vb + (size_t)vrow[j] * T_ + n1 + vcol[j], &lV[cur ^ 1][(tid + j * 256) * 8]);
    }
    const unsigned short* lKc = lK[cur];
    const unsigned short* lVc = lV[cur];
    // ---- QK^T ----
    f32x4 s[2][4] = {};
    __builtin_amdgcn_s_setprio(1);
#pragma unroll
    for (int ct = 0; ct < 4; ct++) {
      short8 kf[4];
#pragma unroll
      for (int ks = 0; ks < 4; ks++)
        kf[ks] = *(const short8*)&lKc[ks * 2048 + (ct * 16 + l16) * 32 + (quad * 8 ^ sw)];
#pragma unroll
      for (int ks = 0; ks < 4; ks++) {
        s[0][ct] = __builtin_amdgcn_mfma_f32_16x16x32_bf16(qf[0][ks], kf[ks], s[0][ct], 0, 0, 0);
        s[1][ct] = __builtin_amdgcn_mfma_f32_16x16x32_bf16(qf[1][ks], kf[ks], s[1][ct], 0, 0, 0);
      }
    }
    __builtin_amdgcn_s_setprio(0);
    // ---- causal mask on raw scores ----
    if (kt >= 2 * qt) {
#pragma unroll
      for (int mt = 0; mt < 2; mt++)
#pragma unroll
        for (int ct = 0; ct < 4; ct++) {
          int n = n0 + ct * 16 + l16;
#pragma unroll
          for (int r = 0; r < 4; r++) {
            int q = qrow0 + mt * 16 + quad * 4 + r;
            if (n > q) s[mt][ct][r] = -1e30f;
          }
        }
    }
    // ---- online max (cross-lane) + alpha; exp via fma-folded scale ----
    float alpha[2][4], msc[2][4];
#pragma unroll
    for (int mt = 0; mt < 2; mt++)
#pragma unroll
      for (int r = 0; r < 4; r++) {
        float v = fmaxf(fmaxf(s[mt][0][r], s[mt][1][r]), fmaxf(s[mt][2][r], s[mt][3][r]));
#pragma unroll
        for (int off = 1; off < 16; off <<= 1)
          v = fmaxf(v, __shfl_xor(v, off));
        float mn = fmaxf(m_r[mt][r], v);
        alpha[mt][r] = exp2f((m_r[mt][r] - mn) * sc);
        m_r[mt][r] = mn;
        msc[mt][r] = mn * sc;
      }
#pragma unroll
    for (int mt = 0; mt < 2; mt++)
#pragma unroll
      for (int ct = 0; ct < 4; ct++)
#pragma unroll
        for (int r = 0; r < 4; r++)
          s[mt][ct][r] = exp2f(fmaf(s[mt][ct][r], sc, -msc[mt][r]));
    // ---- per-lane l partials (reduced once in epilogue) + o rescale ----
#pragma unroll
    for (int mt = 0; mt < 2; mt++)
#pragma unroll
      for (int r = 0; r < 4; r++)
        l_r[mt][r] = l_r[mt][r] * alpha[mt][r] +
                     (s[mt][0][r] + s[mt][1][r]) + (s[mt][2][r] + s[mt][3][r]);
#pragma unroll
    for (int mt = 0; mt < 2; mt++)
#pragma unroll
      for (int dt = 0; dt < 8; dt++)
#pragma unroll
        for (int r = 0; r < 4; r++)
          o[mt][dt][r] *= alpha[mt][r];
    // ---- P m-tile 0 (wave-private lP; no block barrier needed) ----
#pragma unroll
    for (int ct = 0; ct < 4; ct++)
#pragma unroll
      for (int r = 0; r < 4; r++)
        pb[(quad * 4 + r) * 72 + ct * 16 + l16] = f2bf(s[0][ct][r]);
    __builtin_amdgcn_s_waitcnt(0xC07F);  // lgkmcnt(0): P0 writes visible
    short8 pa0[2];
#pragma unroll
    for (int ks2 = 0; ks2 < 2; ks2++)
      pa0[ks2] = *(const short8*)&pb[l16 * 72 + ks2 * 32 + quad * 8];
    __builtin_amdgcn_s_waitcnt(0xC07F);  // pa0 data returned before region reuse
    asm volatile("" ::: "memory");
    // ---- P m-tile 1 (same per-wave region, sequential reuse) ----
#pragma unroll
    for (int ct = 0; ct < 4; ct++)
#pragma unroll
      for (int r = 0; r < 4; r++)
        pb[(quad * 4 + r) * 72 + ct * 16 + l16] = f2bf(s[1][ct][r]);
    __builtin_amdgcn_s_waitcnt(0xC07F);  // lgkmcnt(0): P1 writes visible
    short8 pa1[2];
#pragma unroll
    for (int ks2 = 0; ks2 < 2; ks2++)
      pa1[ks2] = *(const short8*)&pb[l16 * 72 + ks2 * 32 + quad * 8];
    // ---- PV: V fragments read once, feed both m-tiles ----
    __builtin_amdgcn_s_setprio(1);
#pragma unroll
    for (int dt = 0; dt < 8; dt++) {
#pragma unroll
      for (int ks2 = 0; ks2 < 2; ks2++) {
        short8 vf = *(const short8*)&lVc[ks2 * 4096 + (dt * 16 + l16) * 32 + (quad * 8 ^ sw)];
        o[0][dt] = __builtin_amdgcn_mfma_f32_16x16x32_bf16(pa0[ks2], vf, o[0][dt], 0, 0, 0);
        o[1][dt] = __builtin_amdgcn_mfma_f32_16x16x32_bf16(pa1[ks2], vf, o[1][dt], 0, 0, 0);
      }
    }
    __builtin_amdgcn_s_setprio(0);
    // ---- single sync point per tile: next buffer staged + everyone done ----
    if (kt + 1 < ntile) {
      asm volatile("s_waitcnt vmcnt(0)" ::: "memory");
      __syncthreads();
      cur ^= 1;
    }
  }
  // epilogue: reduce per-lane l partials across the 16-lane row group
#pragma unroll
  for (int mt = 0; mt < 2; mt++)
#pragma unroll
    for (int r = 0; r < 4; r++) {
      float v = l_r[mt][r];
#pragma unroll
      for (int off = 1; off < 16; off <<= 1)
        v += __shfl_xor(v, off);
      l_r[mt][r] = v;
    }
#pragma unroll
  for (int mt = 0; mt < 2; mt++)
#pragma unroll
    for (int r = 0; r < 4; r++) {
      int q = qrow0 + mt * 16 + quad * 4 + r;
      float inv = 1.f / l_r[mt][r];
      size_t base = ((size_t)(b * 1024 + q)) * 2048 + h * 128 + l16;
#pragma unroll
      for (int dt = 0; dt < 8; dt++)
        Y[base + dt * 16] = f2bf(o[mt][dt][r] * inv);
    }
}

extern "C" void kernel_launch(void* const* d_in, const int* in_sizes, int n_in,
                              void* d_out, int out_size, void* d_ws, size_t ws_size,
                              hipStream_t stream) {
  const float* x    = (const float*)d_in[0];
  const float* wq   = (const float*)d_in[1];
  const float* wk   = (const float*)d_in[2];
  const float* wv   = (const float*)d_in[3];
  const float* wo   = (const float*)d_in[4];
  const float* sinp = (const float*)d_in[5];
  const float* cosp = (const float*)d_in[6];

  char* ws = (char*)d_ws;
  unsigned short* WCATT = (unsigned short*)(ws);                 // [3072][2048] bf16
  unsigned short* WOT   = (unsigned short*)(ws + 12582912);      // [2048][2048] bf16
  unsigned short* XBF   = (unsigned short*)(ws + 20971520);      // [8192][2048] bf16
  unsigned short* QKV   = (unsigned short*)(ws + 54525952);      // [8192][3072] bf16
  unsigned short* KATT  = (unsigned short*)(ws + 104857600);     // [8*4][1024][128]
  unsigned short* VT    = (unsigned short*)(ws + 113246208);     // [8*4][128][1024]
  unsigned short* QATT  = XBF;  // alias: x_bf16 dead after GEMM1
  unsigned short* Y     = QKV;  // alias: qkv dead after rope+vtpose

  dim3 tb(32, 8);
  cvt_bf16_kernel<<<16384, 256, 0, stream>>>(x, XBF);
  tpose_f32_bf16<<<dim3(64, 64), tb, 0, stream>>>(wq, WCATT, 2048, 2048);
  tpose_f32_bf16<<<dim3(16, 64), tb, 0, stream>>>(wk, WCATT + (size_t)2048 * 2048, 512, 2048);
  tpose_f32_bf16<<<dim3(16, 64), tb, 0, stream>>>(wv, WCATT + (size_t)2560 * 2048, 512, 2048);
  tpose_f32_bf16<<<dim3(64, 64), tb, 0, stream>>>(wo, WOT, 2048, 2048);
  gemm_bf16<0><<<dim3(24, 64), 256, 0, stream>>>(XBF, WCATT, QKV, 3072);
  rope_kernel<<<8192, 256, 0, stream>>>(QKV, sinp, cosp, QATT, KATT);
  vtpose<<<dim3(16, 32, 8), tb, 0, stream>>>(QKV, VT);
  attn_kernel<<<dim3(8, 128), 256, 0, stream>>>(QATT, KATT, VT, Y);
  gemm_bf16<1><<<dim3(16, 64), 256, 0, stream>>>(Y, WOT, d_out, 2048);
}

// Round 4
// 478.454 us; speedup vs baseline: 1.1845x; 1.1028x over previous
//
#include <hip/hip_runtime.h>

typedef __attribute__((ext_vector_type(8))) short short8;
typedef __attribute__((ext_vector_type(4))) float f32x4;

#define B_    8
#define T_    1024
#define C_    2048
#define H_    16
#define HKV_  4
#define HD_   128
#define M_    8192
#define NQKV_ 3072
#define KDIM_ 2048

__device__ __forceinline__ unsigned short f2bf(float f) {
  unsigned u = __float_as_uint(f);
  u += 0x7FFF + ((u >> 16) & 1);
  return (unsigned short)(u >> 16);
}
__device__ __forceinline__ float bf2f(unsigned short h) {
  return __uint_as_float(((unsigned)h) << 16);
}

__device__ __forceinline__ void async16(const unsigned short* g, unsigned short* l) {
  __builtin_amdgcn_global_load_lds(
      (const unsigned int __attribute__((address_space(1)))*)g,
      (unsigned int __attribute__((address_space(3)))*)l,
      16, 0, 0);
}

// ---------------- fp32 -> bf16 straight convert (x) ----------------
__global__ __launch_bounds__(256) void cvt_bf16_kernel(const float* __restrict__ in,
                                                       unsigned short* __restrict__ out) {
  int idx = blockIdx.x * 256 + threadIdx.x;
  float4 v = ((const float4*)in)[idx];
  ushort4 o;
  o.x = f2bf(v.x); o.y = f2bf(v.y); o.z = f2bf(v.z); o.w = f2bf(v.w);
  ((ushort4*)out)[idx] = o;
}

// ------- fp32 [R][Cc] -> bf16 transposed out[c*ldo + r] (weights) -------
__global__ __launch_bounds__(256) void tpose_f32_bf16(const float* __restrict__ in,
                                                      unsigned short* __restrict__ out,
                                                      int Cc, int ldo) {
  __shared__ unsigned short tile[32][33];
  int c0 = blockIdx.x * 32, r0 = blockIdx.y * 32;
  int tx = threadIdx.x, ty = threadIdx.y;
#pragma unroll
  for (int j = 0; j < 4; j++)
    tile[ty + j * 8][tx] = f2bf(in[(size_t)(r0 + ty + j * 8) * Cc + c0 + tx]);
  __syncthreads();
#pragma unroll
  for (int j = 0; j < 4; j++)
    out[(size_t)(c0 + ty + j * 8) * ldo + r0 + tx] = tile[tx][ty + j * 8];
}

// ------- bf16 V-part of qkv -> vT[b][c][t] (per-batch transpose) -------
__global__ __launch_bounds__(256) void vtpose(const unsigned short* __restrict__ qkv,
                                              unsigned short* __restrict__ vt) {
  __shared__ unsigned short tile[32][33];
  int b = blockIdx.z;
  int c0 = blockIdx.x * 32, t0 = blockIdx.y * 32;
  int tx = threadIdx.x, ty = threadIdx.y;
  const unsigned short* src = qkv + (size_t)b * T_ * NQKV_ + 2560;
#pragma unroll
  for (int j = 0; j < 4; j++)
    tile[ty + j * 8][tx] = src[(size_t)(t0 + ty + j * 8) * NQKV_ + c0 + tx];
  __syncthreads();
  unsigned short* dst = vt + (size_t)b * 512 * T_;
#pragma unroll
  for (int j = 0; j < 4; j++)
    dst[(size_t)(c0 + ty + j * 8) * T_ + t0 + tx] = tile[tx][ty + j * 8];
}

// ------- RoPE + relayout: qkv[m][3072] -> qatt[b][h][t][d], katt[b][kh][t][d] -------
__global__ __launch_bounds__(256) void rope_kernel(const unsigned short* __restrict__ qkv,
                                                   const float* __restrict__ sinp,
                                                   const float* __restrict__ cosp,
                                                   unsigned short* __restrict__ qatt,
                                                   unsigned short* __restrict__ katt) {
  int m = blockIdx.x;
  int b = m >> 10, t = m & 1023;
  int tid = threadIdx.x;
  int d = tid & 63;
  const unsigned short* row = qkv + (size_t)m * NQKV_;
  float c0 = cosp[t * 128 + d], s0 = sinp[t * 128 + d];
  float c1 = cosp[t * 128 + d + 64], s1 = sinp[t * 128 + d + 64];
#pragma unroll
  for (int h0 = 0; h0 < 16; h0 += 4) {
    int h = h0 + (tid >> 6);
    float x0 = bf2f(row[h * 128 + d]);
    float x1 = bf2f(row[h * 128 + d + 64]);
    size_t o = ((size_t)(b * 16 + h) * 1024 + t) * 128 + d;
    qatt[o]      = f2bf(x0 * c0 - x1 * s0);
    qatt[o + 64] = f2bf(x1 * c1 + x0 * s1);
  }
  {
    int kh = tid >> 6;
    float x0 = bf2f(row[2048 + kh * 128 + d]);
    float x1 = bf2f(row[2048 + kh * 128 + d + 64]);
    size_t o = ((size_t)(b * 4 + kh) * 1024 + t) * 128 + d;
    katt[o]      = f2bf(x0 * c0 - x1 * s0);
    katt[o + 64] = f2bf(x1 * c1 + x0 * s1);
  }
}

// ------- m97-style GEMM: C[M x N] = A[M x K] * BT[N x K]^T, K=2048 -------
template <int OUTF32>
__global__ __launch_bounds__(256) void gemm_bf16(const unsigned short* __restrict__ A,
                                                 const unsigned short* __restrict__ BT,
                                                 void* __restrict__ Cout, int N) {
  __shared__ unsigned short lA[128 * 32];
  __shared__ unsigned short lB[128 * 32];
  const int K = KDIM_;
  int tid = threadIdx.x;
  int lane = tid & 63;
  int w = tid >> 6;
  int quad = lane >> 4, l16 = lane & 15;
  int bm = blockIdx.y, bn = blockIdx.x;
  const unsigned short* Ab = A + (size_t)bm * 128 * K;
  const unsigned short* Bb = BT + (size_t)bn * 128 * K;
  int i0 = tid, i1 = tid + 256;
  int ra0 = i0 >> 2, ca0 = (i0 & 3) * 8;
  int ra1 = i1 >> 2, ca1 = (i1 & 3) * 8;
  int wm = (w >> 1) * 64, wn = (w & 1) * 64;
  f32x4 acc[4][4] = {};
  for (int k0 = 0; k0 < K; k0 += 32) {
    __syncthreads();
    async16(Ab + (size_t)ra0 * K + k0 + ca0, &lA[i0 * 8]);
    async16(Ab + (size_t)ra1 * K + k0 + ca1, &lA[i1 * 8]);
    async16(Bb + (size_t)ra0 * K + k0 + ca0, &lB[i0 * 8]);
    async16(Bb + (size_t)ra1 * K + k0 + ca1, &lB[i1 * 8]);
    __syncthreads();
    short8 af[4], bfr[4];
#pragma unroll
    for (int mt = 0; mt < 4; mt++)
      af[mt] = *(const short8*)&lA[(wm + mt * 16 + l16) * 32 + quad * 8];
#pragma unroll
    for (int nt = 0; nt < 4; nt++)
      bfr[nt] = *(const short8*)&lB[(wn + nt * 16 + l16) * 32 + quad * 8];
#pragma unroll
    for (int mt = 0; mt < 4; mt++)
#pragma unroll
      for (int nt = 0; nt < 4; nt++)
        acc[mt][nt] = __builtin_amdgcn_mfma_f32_16x16x32_bf16(af[mt], bfr[nt], acc[mt][nt], 0, 0, 0);
  }
#pragma unroll
  for (int mt = 0; mt < 4; mt++) {
#pragma unroll
    for (int nt = 0; nt < 4; nt++) {
      int n = bn * 128 + wn + nt * 16 + l16;
#pragma unroll
      for (int r = 0; r < 4; r++) {
        int m = bm * 128 + wm + mt * 16 + quad * 4 + r;
        if (OUTF32)
          ((float*)Cout)[(size_t)m * N + n] = acc[mt][nt][r];
        else
          ((unsigned short*)Cout)[(size_t)m * N + n] = f2bf(acc[mt][nt][r]);
      }
    }
  }
}

// ------- flash attention v5: balanced q-tile pairing + pipelined staging -------
// Each block processes TWO q-tiles: qt = 7-p then qt = p, so every block does
// exactly 18 K-tiles (zero imbalance; grid 4x128 = 512 blocks = exactly 2/CU).
// Round-3 counters showed OccupancyPercent 11.7% vs 25% ceiling = ~47% slot
// utilization from the 8x block-duration imbalance; pairing removes the tail.
// Staging double-buffered (prefetch next tile before computing current, one
// vmcnt(0)+barrier per tile). P round-trips through wave-private lP. O-rescale
// skipped when running max unchanged (alpha==1, T13). LDS 73 KB -> 2 blocks/CU.
__global__ __launch_bounds__(256, 2) void attn_kernel(const unsigned short* __restrict__ Q,
                                                      const unsigned short* __restrict__ Km,
                                                      const unsigned short* __restrict__ Vt,
                                                      unsigned short* __restrict__ Y) {
  __shared__ __align__(16) unsigned short lK[2][8192];  // [buf][ks][row][tq][8]
  __shared__ __align__(16) unsigned short lV[2][8192];  // [buf][ks2][d][tq][8]
  __shared__ __align__(16) unsigned short lP[4608];     // [wave][16][72]
  int tid = threadIdx.x;
  int lane = tid & 63, w = tid >> 6;
  int quad = lane >> 4, l16 = lane & 15;
  int pq = blockIdx.x;  // 0..3 -> q-tile pair (7-pq, pq): 18 tiles per block
  int bh = blockIdx.y;
  int b = bh >> 4, h = bh & 15, kh = h & 3;
  const unsigned short* Kb = Km + (size_t)(b * 4 + kh) * T_ * 128;
  const unsigned short* Vb = Vt + (size_t)(b * 4 + kh) * 128 * T_;
  const float sc = 0.12751744690989f;  // log2(e)/sqrt(128)
  unsigned short* pb = &lP[w * 1152];  // per-wave 16-row P region, stride 72
  const int sw = (l16 & 3) * 8;        // read-side granule XOR (shorts)

  // loop-invariant staging index parts (i = tid + j*256)
  int krow[4], kcol[4], vrow[4], vcol[4];
#pragma unroll
  for (int j = 0; j < 4; j++) {
    int i = tid + j * 256;
    int tq = (i & 3) ^ ((i >> 2) & 3);
    krow[j] = (i >> 2) & 63;
    kcol[j] = (i >> 8) * 32 + tq * 8;
    vrow[j] = (i >> 2) & 127;
    vcol[j] = (i >> 9) * 32 + tq * 8;
  }

  for (int ph = 0; ph < 2; ph++) {
    int qt = ph ? pq : 7 - pq;
    int qrow0 = qt * 128 + w * 32;
    const unsigned short* Qb = Q + ((size_t)bh * T_ + qrow0) * 128;
    short8 qf[2][4];
#pragma unroll
    for (int mt = 0; mt < 2; mt++)
#pragma unroll
      for (int ks = 0; ks < 4; ks++)
        qf[mt][ks] = *(const short8*)&Qb[(mt * 16 + l16) * 128 + ks * 32 + quad * 8];
    f32x4 o[2][8] = {};
    float m_r[2][4], l_r[2][4];
#pragma unroll
    for (int mt = 0; mt < 2; mt++)
#pragma unroll
      for (int r = 0; r < 4; r++) {
        m_r[mt][r] = -1e30f;
        l_r[mt][r] = 0.f;
      }
    int ntile = 2 * qt + 2;

    if (ph) __syncthreads();  // phase A's last lV/lP reads done before restage
    // prologue: stage tile 0 into buf 0
#pragma unroll
    for (int j = 0; j < 4; j++)
      async16(Kb + (size_t)krow[j] * 128 + kcol[j], &lK[0][(tid + j * 256) * 8]);
#pragma unroll
    for (int j = 0; j < 4; j++)
      async16(Vb + (size_t)vrow[j] * T_ + vcol[j], &lV[0][(tid + j * 256) * 8]);
    asm volatile("s_waitcnt vmcnt(0)" ::: "memory");
    __syncthreads();

    int cur = 0;
    for (int kt = 0; kt < ntile; kt++) {
      int n0 = kt * 64;
      // issue next tile's staging into the other buffer (latency hides under compute)
      if (kt + 1 < ntile) {
        int n1 = n0 + 64;
#pragma unroll
        for (int j = 0; j < 4; j++)
          async16(Kb + (size_t)(n1 + krow[j]) * 128 + kcol[j], &lK[cur ^ 1][(tid + j * 256) * 8]);
#pragma unroll
        for (int j = 0; j < 4; j++)
          async16(Vb + (size_t)vrow[j] * T_ + n1 + vcol[j], &lV[cur ^ 1][(tid + j * 256) * 8]);
      }
      const unsigned short* lKc = lK[cur];
      const unsigned short* lVc = lV[cur];
      // ---- QK^T ----
      f32x4 s[2][4] = {};
      __builtin_amdgcn_s_setprio(1);
#pragma unroll
      for (int ct = 0; ct < 4; ct++) {
        short8 kf[4];
#pragma unroll
        for (int ks = 0; ks < 4; ks++)
          kf[ks] = *(const short8*)&lKc[ks * 2048 + (ct * 16 + l16) * 32 + (quad * 8 ^ sw)];
#pragma unroll
        for (int ks = 0; ks < 4; ks++) {
          s[0][ct] = __builtin_amdgcn_mfma_f32_16x16x32_bf16(qf[0][ks], kf[ks], s[0][ct], 0, 0, 0);
          s[1][ct] = __builtin_amdgcn_mfma_f32_16x16x32_bf16(qf[1][ks], kf[ks], s[1][ct], 0, 0, 0);
        }
      }
      __builtin_amdgcn_s_setprio(0);
      // ---- causal mask on raw scores ----
      if (kt >= 2 * qt) {
#pragma unroll
        for (int mt = 0; mt < 2; mt++)
#pragma unroll
          for (int ct = 0; ct < 4; ct++) {
            int n = n0 + ct * 16 + l16;
#pragma unroll
            for (int r = 0; r < 4; r++) {
              int q = qrow0 + mt * 16 + quad * 4 + r;
              if (n > q) s[mt][ct][r] = -1e30f;
            }
          }
      }
      // ---- online max (cross-lane) + alpha; exp via fma-folded scale ----
      float alpha[2][4], msc[2][4];
#pragma unroll
      for (int mt = 0; mt < 2; mt++)
#pragma unroll
        for (int r = 0; r < 4; r++) {
          float v = fmaxf(fmaxf(s[mt][0][r], s[mt][1][r]), fmaxf(s[mt][2][r], s[mt][3][r]));
#pragma unroll
          for (int off = 1; off < 16; off <<= 1)
            v = fmaxf(v, __shfl_xor(v, off));
          float mn = fmaxf(m_r[mt][r], v);
          alpha[mt][r] = exp2f((m_r[mt][r] - mn) * sc);
          m_r[mt][r] = mn;
          msc[mt][r] = mn * sc;
        }
#pragma unroll
      for (int mt = 0; mt < 2; mt++)
#pragma unroll
        for (int ct = 0; ct < 4; ct++)
#pragma unroll
          for (int r = 0; r < 4; r++)
            s[mt][ct][r] = exp2f(fmaf(s[mt][ct][r], sc, -msc[mt][r]));
      // ---- P m-tile 0 writes issued first; independent VALU hides their latency ----
#pragma unroll
      for (int ct = 0; ct < 4; ct++)
#pragma unroll
        for (int r = 0; r < 4; r++)
          pb[(quad * 4 + r) * 72 + ct * 16 + l16] = f2bf(s[0][ct][r]);
      // per-lane l partials (reduced once in epilogue)
#pragma unroll
      for (int mt = 0; mt < 2; mt++)
#pragma unroll
        for (int r = 0; r < 4; r++)
          l_r[mt][r] = l_r[mt][r] * alpha[mt][r] +
                       (s[mt][0][r] + s[mt][1][r]) + (s[mt][2][r] + s[mt][3][r]);
      // conditional O-rescale (T13): alpha==1 for all rows once max stabilizes
      bool needr = false;
#pragma unroll
      for (int mt = 0; mt < 2; mt++)
#pragma unroll
        for (int r = 0; r < 4; r++)
          needr |= (alpha[mt][r] != 1.0f);
      if (__any(needr)) {
#pragma unroll
        for (int mt = 0; mt < 2; mt++)
#pragma unroll
          for (int dt = 0; dt < 8; dt++)
#pragma unroll
            for (int r = 0; r < 4; r++)
              o[mt][dt][r] *= alpha[mt][r];
      }
      __builtin_amdgcn_s_waitcnt(0xC07F);  // lgkmcnt(0): P0 writes visible
      short8 pa0[2];
#pragma unroll
      for (int ks2 = 0; ks2 < 2; ks2++)
        pa0[ks2] = *(const short8*)&pb[l16 * 72 + ks2 * 32 + quad * 8];
      __builtin_amdgcn_s_waitcnt(0xC07F);  // pa0 data returned before region reuse
      asm volatile("" ::: "memory");
      // ---- P m-tile 1 (same per-wave region, sequential reuse) ----
#pragma unroll
      for (int ct = 0; ct < 4; ct++)
#pragma unroll
        for (int r = 0; r < 4; r++)
          pb[(quad * 4 + r) * 72 + ct * 16 + l16] = f2bf(s[1][ct][r]);
      __builtin_amdgcn_s_waitcnt(0xC07F);  // lgkmcnt(0): P1 writes visible
      short8 pa1[2];
#pragma unroll
      for (int ks2 = 0; ks2 < 2; ks2++)
        pa1[ks2] = *(const short8*)&pb[l16 * 72 + ks2 * 32 + quad * 8];
      // ---- PV: V fragments read once, feed both m-tiles ----
      __builtin_amdgcn_s_setprio(1);
#pragma unroll
      for (int dt = 0; dt < 8; dt++) {
#pragma unroll
        for (int ks2 = 0; ks2 < 2; ks2++) {
          short8 vf = *(const short8*)&lVc[ks2 * 4096 + (dt * 16 + l16) * 32 + (quad * 8 ^ sw)];
          o[0][dt] = __builtin_amdgcn_mfma_f32_16x16x32_bf16(pa0[ks2], vf, o[0][dt], 0, 0, 0);
          o[1][dt] = __builtin_amdgcn_mfma_f32_16x16x32_bf16(pa1[ks2], vf, o[1][dt], 0, 0, 0);
        }
      }
      __builtin_amdgcn_s_setprio(0);
      // ---- single sync point per tile: next buffer staged + everyone done ----
      if (kt + 1 < ntile) {
        asm volatile("s_waitcnt vmcnt(0)" ::: "memory");
        __syncthreads();
        cur ^= 1;
      }
    }
    // epilogue: reduce per-lane l partials across the 16-lane row group
#pragma unroll
    for (int mt = 0; mt < 2; mt++)
#pragma unroll
      for (int r = 0; r < 4; r++) {
        float v = l_r[mt][r];
#pragma unroll
        for (int off = 1; off < 16; off <<= 1)
          v += __shfl_xor(v, off);
        l_r[mt][r] = v;
      }
#pragma unroll
    for (int mt = 0; mt < 2; mt++)
#pragma unroll
      for (int r = 0; r < 4; r++) {
        int q = qrow0 + mt * 16 + quad * 4 + r;
        float inv = 1.f / l_r[mt][r];
        size_t base = ((size_t)(b * 1024 + q)) * 2048 + h * 128 + l16;
#pragma unroll
        for (int dt = 0; dt < 8; dt++)
          Y[base + dt * 16] = f2bf(o[mt][dt][r] * inv);
      }
  }
}

extern "C" void kernel_launch(void* const* d_in, const int* in_sizes, int n_in,
                              void* d_out, int out_size, void* d_ws, size_t ws_size,
                              hipStream_t stream) {
  const float* x    = (const float*)d_in[0];
  const float* wq   = (const float*)d_in[1];
  const float* wk   = (const float*)d_in[2];
  const float* wv   = (const float*)d_in[3];
  const float* wo   = (const float*)d_in[4];
  const float* sinp = (const float*)d_in[5];
  const float* cosp = (const float*)d_in[6];

  char* ws = (char*)d_ws;
  unsigned short* WCATT = (unsigned short*)(ws);                 // [3072][2048] bf16
  unsigned short* WOT   = (unsigned short*)(ws + 12582912);      // [2048][2048] bf16
  unsigned short* XBF   = (unsigned short*)(ws + 20971520);      // [8192][2048] bf16
  unsigned short* QKV   = (unsigned short*)(ws + 54525952);      // [8192][3072] bf16
  unsigned short* KATT  = (unsigned short*)(ws + 104857600);     // [8*4][1024][128]
  unsigned short* VT    = (unsigned short*)(ws + 113246208);     // [8*4][128][1024]
  unsigned short* QATT  = XBF;  // alias: x_bf16 dead after GEMM1
  unsigned short* Y     = QKV;  // alias: qkv dead after rope+vtpose

  dim3 tb(32, 8);
  cvt_bf16_kernel<<<16384, 256, 0, stream>>>(x, XBF);
  tpose_f32_bf16<<<dim3(64, 64), tb, 0, stream>>>(wq, WCATT, 2048, 2048);
  tpose_f32_bf16<<<dim3(16, 64), tb, 0, stream>>>(wk, WCATT + (size_t)2048 * 2048, 512, 2048);
  tpose_f32_bf16<<<dim3(16, 64), tb, 0, stream>>>(wv, WCATT + (size_t)2560 * 2048, 512, 2048);
  tpose_f32_bf16<<<dim3(64, 64), tb, 0, stream>>>(wo, WOT, 2048, 2048);
  gemm_bf16<0><<<dim3(24, 64), 256, 0, stream>>>(XBF, WCATT, QKV, 3072);
  rope_kernel<<<8192, 256, 0, stream>>>(QKV, sinp, cosp, QATT, KATT);
  vtpose<<<dim3(16, 32, 8), tb, 0, stream>>>(QKV, VT);
  attn_kernel<<<dim3(4, 128), 256, 0, stream>>>(QATT, KATT, VT, Y);
  gemm_bf16<1><<<dim3(16, 64), 256, 0, stream>>>(Y, WOT, d_out, 2048);
}

// Round 5
// 466.733 us; speedup vs baseline: 1.2142x; 1.0251x over previous
//
#include <hip/hip_runtime.h>

typedef __attribute__((ext_vector_type(8))) short short8;
typedef __attribute__((ext_vector_type(4))) float f32x4;

#define B_    8
#define T_    1024
#define C_    2048
#define H_    16
#define HKV_  4
#define HD_   128
#define M_    8192
#define NQKV_ 3072
#define KDIM_ 2048

__device__ __forceinline__ unsigned short f2bf(float f) {
  unsigned u = __float_as_uint(f);
  u += 0x7FFF + ((u >> 16) & 1);
  return (unsigned short)(u >> 16);
}
__device__ __forceinline__ float bf2f(unsigned short h) {
  return __uint_as_float(((unsigned)h) << 16);
}

__device__ __forceinline__ void async16(const unsigned short* g, unsigned short* l) {
  __builtin_amdgcn_global_load_lds(
      (const unsigned int __attribute__((address_space(1)))*)g,
      (unsigned int __attribute__((address_space(3)))*)l,
      16, 0, 0);
}

// ---------------- fp32 -> bf16 straight convert (x) ----------------
__global__ __launch_bounds__(256) void cvt_bf16_kernel(const float* __restrict__ in,
                                                       unsigned short* __restrict__ out) {
  int idx = blockIdx.x * 256 + threadIdx.x;
  float4 v = ((const float4*)in)[idx];
  ushort4 o;
  o.x = f2bf(v.x); o.y = f2bf(v.y); o.z = f2bf(v.z); o.w = f2bf(v.w);
  ((ushort4*)out)[idx] = o;
}

// ------- fp32 [R][Cc] -> bf16 transposed out[c*ldo + r] (weights) -------
__global__ __launch_bounds__(256) void tpose_f32_bf16(const float* __restrict__ in,
                                                      unsigned short* __restrict__ out,
                                                      int Cc, int ldo) {
  __shared__ unsigned short tile[32][33];
  int c0 = blockIdx.x * 32, r0 = blockIdx.y * 32;
  int tx = threadIdx.x, ty = threadIdx.y;
#pragma unroll
  for (int j = 0; j < 4; j++)
    tile[ty + j * 8][tx] = f2bf(in[(size_t)(r0 + ty + j * 8) * Cc + c0 + tx]);
  __syncthreads();
#pragma unroll
  for (int j = 0; j < 4; j++)
    out[(size_t)(c0 + ty + j * 8) * ldo + r0 + tx] = tile[tx][ty + j * 8];
}

// ------- bf16 V-part of qkv -> vT[b][c][t] (per-batch transpose) -------
__global__ __launch_bounds__(256) void vtpose(const unsigned short* __restrict__ qkv,
                                              unsigned short* __restrict__ vt) {
  __shared__ unsigned short tile[32][33];
  int b = blockIdx.z;
  int c0 = blockIdx.x * 32, t0 = blockIdx.y * 32;
  int tx = threadIdx.x, ty = threadIdx.y;
  const unsigned short* src = qkv + (size_t)b * T_ * NQKV_ + 2560;
#pragma unroll
  for (int j = 0; j < 4; j++)
    tile[ty + j * 8][tx] = src[(size_t)(t0 + ty + j * 8) * NQKV_ + c0 + tx];
  __syncthreads();
  unsigned short* dst = vt + (size_t)b * 512 * T_;
#pragma unroll
  for (int j = 0; j < 4; j++)
    dst[(size_t)(c0 + ty + j * 8) * T_ + t0 + tx] = tile[tx][ty + j * 8];
}

// ------- RoPE + relayout: qkv[m][3072] -> qatt[b][h][t][d], katt[b][kh][t][d] -------
__global__ __launch_bounds__(256) void rope_kernel(const unsigned short* __restrict__ qkv,
                                                   const float* __restrict__ sinp,
                                                   const float* __restrict__ cosp,
                                                   unsigned short* __restrict__ qatt,
                                                   unsigned short* __restrict__ katt) {
  int m = blockIdx.x;
  int b = m >> 10, t = m & 1023;
  int tid = threadIdx.x;
  int d = tid & 63;
  const unsigned short* row = qkv + (size_t)m * NQKV_;
  float c0 = cosp[t * 128 + d], s0 = sinp[t * 128 + d];
  float c1 = cosp[t * 128 + d + 64], s1 = sinp[t * 128 + d + 64];
#pragma unroll
  for (int h0 = 0; h0 < 16; h0 += 4) {
    int h = h0 + (tid >> 6);
    float x0 = bf2f(row[h * 128 + d]);
    float x1 = bf2f(row[h * 128 + d + 64]);
    size_t o = ((size_t)(b * 16 + h) * 1024 + t) * 128 + d;
    qatt[o]      = f2bf(x0 * c0 - x1 * s0);
    qatt[o + 64] = f2bf(x1 * c1 + x0 * s1);
  }
  {
    int kh = tid >> 6;
    float x0 = bf2f(row[2048 + kh * 128 + d]);
    float x1 = bf2f(row[2048 + kh * 128 + d + 64]);
    size_t o = ((size_t)(b * 4 + kh) * 1024 + t) * 128 + d;
    katt[o]      = f2bf(x0 * c0 - x1 * s0);
    katt[o + 64] = f2bf(x1 * c1 + x0 * s1);
  }
}

// ------- GEMM v2: 256x128 tile, BK=64, 8 waves, phase-locked pipeline -------
// C[M x N] = A[M x K] * BT[N x K]^T, K=2048. 512 threads, waves 4M x 2N,
// per-wave 64x64 output (acc[4][4]). Double-buffered LDS (96 KB, 1 block/CU).
// Next K-tile's 6 global_load_lds issued at phase 0 of current tile; single
// vmcnt(0)+s_barrier at tile end (issue-to-wait = 2 MFMA phases ~400 cy).
// k-granule XOR swizzle k^=((row>>2)&3)*16 applied on BOTH the pre-swizzled
// global stage source and the ds_read address (involution): all 64 lanes'
// ds_read_b128 start-words spread uniformly over the 8 bank slots.
// Raw s_barrier (no implicit vmcnt drain) keeps waves phase-locked; setprio
// around MFMA clusters (T5 needs the phase split). XCD-bijective block swizzle.
template <int OUTF32>
__global__ __launch_bounds__(512, 2) void gemm_v2(const unsigned short* __restrict__ A,
                                                  const unsigned short* __restrict__ BT,
                                                  void* __restrict__ Cout, int N) {
  __shared__ __align__(16) unsigned short lA[2][256 * 64];
  __shared__ __align__(16) unsigned short lB[2][128 * 64];
  const int K = KDIM_;
  int tid = threadIdx.x;
  int lane = tid & 63;
  int w = tid >> 6;
  int quad = lane >> 4, l16 = lane & 15;
  int wm = w >> 1, wn = w & 1;  // 4M x 2N wave grid
  // XCD-aware bijective swizzle (nwg % 8 == 0 for both grids)
  int gx = gridDim.x;
  int nwg = gx * gridDim.y;
  int lin = blockIdx.y * gx + blockIdx.x;
  int cpx = nwg >> 3;
  int swz = (lin & 7) * cpx + (lin >> 3);
  int bm = swz / gx, bn = swz % gx;
  const unsigned short* Ab = A + (size_t)bm * 256 * K;
  const unsigned short* Bb = BT + (size_t)bn * 128 * K;
  // staging: LDS linear pos (j*512+tid)*16B -> row=(j*512+tid)/8, klin=(tid&7)*8
  int klin = (tid & 7) * 8;
  int arow[4], acol[4];
#pragma unroll
  for (int j = 0; j < 4; j++) {
    int r = (j * 512 + tid) >> 3;
    arow[j] = r;
    acol[j] = klin ^ (((r >> 2) & 3) * 16);  // pre-swizzled global source
  }
  int brow[2], bcol[2];
#pragma unroll
  for (int j = 0; j < 2; j++) {
    int r = (j * 512 + tid) >> 3;
    brow[j] = r;
    bcol[j] = klin ^ (((r >> 2) & 3) * 16);
  }
  const int rsw = ((l16 >> 2) & 3) * 16;  // read-side swizzle (same involution)
  f32x4 acc[4][4] = {};
  // prologue: stage tile 0 into buf 0
#pragma unroll
  for (int j = 0; j < 4; j++)
    async16(Ab + (size_t)arow[j] * K + acol[j], &lA[0][(j * 512 + tid) * 8]);
#pragma unroll
  for (int j = 0; j < 2; j++)
    async16(Bb + (size_t)brow[j] * K + bcol[j], &lB[0][(j * 512 + tid) * 8]);
  asm volatile("s_waitcnt vmcnt(0)" ::: "memory");
  __builtin_amdgcn_s_barrier();
  int cur = 0;
  for (int kt = 0; kt < 32; kt++) {
    const unsigned short* pA = lA[cur];
    const unsigned short* pB = lB[cur];
    // ---- phase 0: ds-read A m0-1 + all B; issue next tile's staging ----
    short8 af[2][2], bfr[4][2];
#pragma unroll
    for (int mt = 0; mt < 2; mt++)
#pragma unroll
      for (int ks = 0; ks < 2; ks++)
        af[mt][ks] = *(const short8*)&pA[(wm * 64 + mt * 16 + l16) * 64 +
                                         ((ks * 32 + quad * 8) ^ rsw)];
#pragma unroll
    for (int nt = 0; nt < 4; nt++)
#pragma unroll
      for (int ks = 0; ks < 2; ks++)
        bfr[nt][ks] = *(const short8*)&pB[(wn * 64 + nt * 16 + l16) * 64 +
                                          ((ks * 32 + quad * 8) ^ rsw)];
    if (kt < 31) {
      int k0 = (kt + 1) * 64;
#pragma unroll
      for (int j = 0; j < 4; j++)
        async16(Ab + (size_t)arow[j] * K + k0 + acol[j], &lA[cur ^ 1][(j * 512 + tid) * 8]);
#pragma unroll
      for (int j = 0; j < 2; j++)
        async16(Bb + (size_t)brow[j] * K + k0 + bcol[j], &lB[cur ^ 1][(j * 512 + tid) * 8]);
    }
    __builtin_amdgcn_s_barrier();
    __builtin_amdgcn_s_setprio(1);
#pragma unroll
    for (int mt = 0; mt < 2; mt++)
#pragma unroll
      for (int nt = 0; nt < 4; nt++)
#pragma unroll
        for (int ks = 0; ks < 2; ks++)
          acc[mt][nt] = __builtin_amdgcn_mfma_f32_16x16x32_bf16(af[mt][ks], bfr[nt][ks],
                                                                acc[mt][nt], 0, 0, 0);
    __builtin_amdgcn_s_setprio(0);
    __builtin_amdgcn_s_barrier();
    // ---- phase 1: ds-read A m2-3; MFMA second half ----
    short8 ag[2][2];
#pragma unroll
    for (int mt = 0; mt < 2; mt++)
#pragma unroll
      for (int ks = 0; ks < 2; ks++)
        ag[mt][ks] = *(const short8*)&pA[(wm * 64 + (mt + 2) * 16 + l16) * 64 +
                                         ((ks * 32 + quad * 8) ^ rsw)];
    __builtin_amdgcn_s_setprio(1);
#pragma unroll
    for (int mt = 0; mt < 2; mt++)
#pragma unroll
      for (int nt = 0; nt < 4; nt++)
#pragma unroll
        for (int ks = 0; ks < 2; ks++)
          acc[mt + 2][nt] = __builtin_amdgcn_mfma_f32_16x16x32_bf16(ag[mt][ks], bfr[nt][ks],
                                                                    acc[mt + 2][nt], 0, 0, 0);
    __builtin_amdgcn_s_setprio(0);
    // ---- tile end: next buffer staged (own loads drained) + all waves done ----
    asm volatile("s_waitcnt vmcnt(0)" ::: "memory");
    __builtin_amdgcn_s_barrier();
    cur ^= 1;
  }
#pragma unroll
  for (int mt = 0; mt < 4; mt++) {
#pragma unroll
    for (int nt = 0; nt < 4; nt++) {
      int n = bn * 128 + wn * 64 + nt * 16 + l16;
#pragma unroll
      for (int r = 0; r < 4; r++) {
        int m = bm * 256 + wm * 64 + mt * 16 + quad * 4 + r;
        if (OUTF32)
          ((float*)Cout)[(size_t)m * N + n] = acc[mt][nt][r];
        else
          ((unsigned short*)Cout)[(size_t)m * N + n] = f2bf(acc[mt][nt][r]);
      }
    }
  }
}

// ------- flash attention v5: balanced q-tile pairing + pipelined staging -------
__global__ __launch_bounds__(256, 2) void attn_kernel(const unsigned short* __restrict__ Q,
                                                      const unsigned short* __restrict__ Km,
                                                      const unsigned short* __restrict__ Vt,
                                                      unsigned short* __restrict__ Y) {
  __shared__ __align__(16) unsigned short lK[2][8192];  // [buf][ks][row][tq][8]
  __shared__ __align__(16) unsigned short lV[2][8192];  // [buf][ks2][d][tq][8]
  __shared__ __align__(16) unsigned short lP[4608];     // [wave][16][72]
  int tid = threadIdx.x;
  int lane = tid & 63, w = tid >> 6;
  int quad = lane >> 4, l16 = lane & 15;
  int pq = blockIdx.x;  // 0..3 -> q-tile pair (7-pq, pq): 18 tiles per block
  int bh = blockIdx.y;
  int b = bh >> 4, h = bh & 15, kh = h & 3;
  const unsigned short* Kb = Km + (size_t)(b * 4 + kh) * T_ * 128;
  const unsigned short* Vb = Vt + (size_t)(b * 4 + kh) * 128 * T_;
  const float sc = 0.12751744690989f;  // log2(e)/sqrt(128)
  unsigned short* pb = &lP[w * 1152];  // per-wave 16-row P region, stride 72
  const int sw = (l16 & 3) * 8;        // read-side granule XOR (shorts)

  // loop-invariant staging index parts (i = tid + j*256)
  int krow[4], kcol[4], vrow[4], vcol[4];
#pragma unroll
  for (int j = 0; j < 4; j++) {
    int i = tid + j * 256;
    int tq = (i & 3) ^ ((i >> 2) & 3);
    krow[j] = (i >> 2) & 63;
    kcol[j] = (i >> 8) * 32 + tq * 8;
    vrow[j] = (i >> 2) & 127;
    vcol[j] = (i >> 9) * 32 + tq * 8;
  }

  for (int ph = 0; ph < 2; ph++) {
    int qt = ph ? pq : 7 - pq;
    int qrow0 = qt * 128 + w * 32;
    const unsigned short* Qb = Q + ((size_t)bh * T_ + qrow0) * 128;
    short8 qf[2][4];
#pragma unroll
    for (int mt = 0; mt < 2; mt++)
#pragma unroll
      for (int ks = 0; ks < 4; ks++)
        qf[mt][ks] = *(const short8*)&Qb[(mt * 16 + l16) * 128 + ks * 32 + quad * 8];
    f32x4 o[2][8] = {};
    float m_r[2][4], l_r[2][4];
#pragma unroll
    for (int mt = 0; mt < 2; mt++)
#pragma unroll
      for (int r = 0; r < 4; r++) {
        m_r[mt][r] = -1e30f;
        l_r[mt][r] = 0.f;
      }
    int ntile = 2 * qt + 2;

    if (ph) __syncthreads();  // phase A's last lV/lP reads done before restage
    // prologue: stage tile 0 into buf 0
#pragma unroll
    for (int j = 0; j < 4; j++)
      async16(Kb + (size_t)krow[j] * 128 + kcol[j], &lK[0][(tid + j * 256) * 8]);
#pragma unroll
    for (int j = 0; j < 4; j++)
      async16(Vb + (size_t)vrow[j] * T_ + vcol[j], &lV[0][(tid + j * 256) * 8]);
    asm volatile("s_waitcnt vmcnt(0)" ::: "memory");
    __syncthreads();

    int cur = 0;
    for (int kt = 0; kt < ntile; kt++) {
      int n0 = kt * 64;
      // issue next tile's staging into the other buffer (latency hides under compute)
      if (kt + 1 < ntile) {
        int n1 = n0 + 64;
#pragma unroll
        for (int j = 0; j < 4; j++)
          async16(Kb + (size_t)(n1 + krow[j]) * 128 + kcol[j], &lK[cur ^ 1][(tid + j * 256) * 8]);
#pragma unroll
        for (int j = 0; j < 4; j++)
          async16(Vb + (size_t)vrow[j] * T_ + n1 + vcol[j], &lV[cur ^ 1][(tid + j * 256) * 8]);
      }
      const unsigned short* lKc = lK[cur];
      const unsigned short* lVc = lV[cur];
      // ---- QK^T ----
      f32x4 s[2][4] = {};
      __builtin_amdgcn_s_setprio(1);
#pragma unroll
      for (int ct = 0; ct < 4; ct++) {
        short8 kf[4];
#pragma unroll
        for (int ks = 0; ks < 4; ks++)
          kf[ks] = *(const short8*)&lKc[ks * 2048 + (ct * 16 + l16) * 32 + (quad * 8 ^ sw)];
#pragma unroll
        for (int ks = 0; ks < 4; ks++) {
          s[0][ct] = __builtin_amdgcn_mfma_f32_16x16x32_bf16(qf[0][ks], kf[ks], s[0][ct], 0, 0, 0);
          s[1][ct] = __builtin_amdgcn_mfma_f32_16x16x32_bf16(qf[1][ks], kf[ks], s[1][ct], 0, 0, 0);
        }
      }
      __builtin_amdgcn_s_setprio(0);
      // ---- causal mask on raw scores ----
      if (kt >= 2 * qt) {
#pragma unroll
        for (int mt = 0; mt < 2; mt++)
#pragma unroll
          for (int ct = 0; ct < 4; ct++) {
            int n = n0 + ct * 16 + l16;
#pragma unroll
            for (int r = 0; r < 4; r++) {
              int q = qrow0 + mt * 16 + quad * 4 + r;
              if (n > q) s[mt][ct][r] = -1e30f;
            }
          }
      }
      // ---- online max (cross-lane) + alpha; exp via fma-folded scale ----
      float alpha[2][4], msc[2][4];
#pragma unroll
      for (int mt = 0; mt < 2; mt++)
#pragma unroll
        for (int r = 0; r < 4; r++) {
          float v = fmaxf(fmaxf(s[mt][0][r], s[mt][1][r]), fmaxf(s[mt][2][r], s[mt][3][r]));
#pragma unroll
          for (int off = 1; off < 16; off <<= 1)
            v = fmaxf(v, __shfl_xor(v, off));
          float mn = fmaxf(m_r[mt][r], v);
          alpha[mt][r] = exp2f((m_r[mt][r] - mn) * sc);
          m_r[mt][r] = mn;
          msc[mt][r] = mn * sc;
        }
#pragma unroll
      for (int mt = 0; mt < 2; mt++)
#pragma unroll
        for (int ct = 0; ct < 4; ct++)
#pragma unroll
          for (int r = 0; r < 4; r++)
            s[mt][ct][r] = exp2f(fmaf(s[mt][ct][r], sc, -msc[mt][r]));
      // ---- P m-tile 0 writes issued first; independent VALU hides their latency ----
#pragma unroll
      for (int ct = 0; ct < 4; ct++)
#pragma unroll
        for (int r = 0; r < 4; r++)
          pb[(quad * 4 + r) * 72 + ct * 16 + l16] = f2bf(s[0][ct][r]);
      // per-lane l partials (reduced once in epilogue)
#pragma unroll
      for (int mt = 0; mt < 2; mt++)
#pragma unroll
        for (int r = 0; r < 4; r++)
          l_r[mt][r] = l_r[mt][r] * alpha[mt][r] +
                       (s[mt][0][r] + s[mt][1][r]) + (s[mt][2][r] + s[mt][3][r]);
      // conditional O-rescale (T13): alpha==1 for all rows once max stabilizes
      bool needr = false;
#pragma unroll
      for (int mt = 0; mt < 2; mt++)
#pragma unroll
        for (int r = 0; r < 4; r++)
          needr |= (alpha[mt][r] != 1.0f);
      if (__any(needr)) {
#pragma unroll
        for (int mt = 0; mt < 2; mt++)
#pragma unroll
          for (int dt = 0; dt < 8; dt++)
#pragma unroll
            for (int r = 0; r < 4; r++)
              o[mt][dt][r] *= alpha[mt][r];
      }
      __builtin_amdgcn_s_waitcnt(0xC07F);  // lgkmcnt(0): P0 writes visible
      short8 pa0[2];
#pragma unroll
      for (int ks2 = 0; ks2 < 2; ks2++)
        pa0[ks2] = *(const short8*)&pb[l16 * 72 + ks2 * 32 + quad * 8];
      __builtin_amdgcn_s_waitcnt(0xC07F);  // pa0 data returned before region reuse
      asm volatile("" ::: "memory");
      // ---- P m-tile 1 (same per-wave region, sequential reuse) ----
#pragma unroll
      for (int ct = 0; ct < 4; ct++)
#pragma unroll
        for (int r = 0; r < 4; r++)
          pb[(quad * 4 + r) * 72 + ct * 16 + l16] = f2bf(s[1][ct][r]);
      __builtin_amdgcn_s_waitcnt(0xC07F);  // lgkmcnt(0): P1 writes visible
      short8 pa1[2];
#pragma unroll
      for (int ks2 = 0; ks2 < 2; ks2++)
        pa1[ks2] = *(const short8*)&pb[l16 * 72 + ks2 * 32 + quad * 8];
      // ---- PV: V fragments read once, feed both m-tiles ----
      __builtin_amdgcn_s_setprio(1);
#pragma unroll
      for (int dt = 0; dt < 8; dt++) {
#pragma unroll
        for (int ks2 = 0; ks2 < 2; ks2++) {
          short8 vf = *(const short8*)&lVc[ks2 * 4096 + (dt * 16 + l16) * 32 + (quad * 8 ^ sw)];
          o[0][dt] = __builtin_amdgcn_mfma_f32_16x16x32_bf16(pa0[ks2], vf, o[0][dt], 0, 0, 0);
          o[1][dt] = __builtin_amdgcn_mfma_f32_16x16x32_bf16(pa1[ks2], vf, o[1][dt], 0, 0, 0);
        }
      }
      __builtin_amdgcn_s_setprio(0);
      // ---- single sync point per tile: next buffer staged + everyone done ----
      if (kt + 1 < ntile) {
        asm volatile("s_waitcnt vmcnt(0)" ::: "memory");
        __syncthreads();
        cur ^= 1;
      }
    }
    // epilogue: reduce per-lane l partials across the 16-lane row group
#pragma unroll
    for (int mt = 0; mt < 2; mt++)
#pragma unroll
      for (int r = 0; r < 4; r++) {
        float v = l_r[mt][r];
#pragma unroll
        for (int off = 1; off < 16; off <<= 1)
          v += __shfl_xor(v, off);
        l_r[mt][r] = v;
      }
#pragma unroll
    for (int mt = 0; mt < 2; mt++)
#pragma unroll
      for (int r = 0; r < 4; r++) {
        int q = qrow0 + mt * 16 + quad * 4 + r;
        float inv = 1.f / l_r[mt][r];
        size_t base = ((size_t)(b * 1024 + q)) * 2048 + h * 128 + l16;
#pragma unroll
        for (int dt = 0; dt < 8; dt++)
          Y[base + dt * 16] = f2bf(o[mt][dt][r] * inv);
      }
  }
}

extern "C" void kernel_launch(void* const* d_in, const int* in_sizes, int n_in,
                              void* d_out, int out_size, void* d_ws, size_t ws_size,
                              hipStream_t stream) {
  const float* x    = (const float*)d_in[0];
  const float* wq   = (const float*)d_in[1];
  const float* wk   = (const float*)d_in[2];
  const float* wv   = (const float*)d_in[3];
  const float* wo   = (const float*)d_in[4];
  const float* sinp = (const float*)d_in[5];
  const float* cosp = (const float*)d_in[6];

  char* ws = (char*)d_ws;
  unsigned short* WCATT = (unsigned short*)(ws);                 // [3072][2048] bf16
  unsigned short* WOT   = (unsigned short*)(ws + 12582912);      // [2048][2048] bf16
  unsigned short* XBF   = (unsigned short*)(ws + 20971520);      // [8192][2048] bf16
  unsigned short* QKV   = (unsigned short*)(ws + 54525952);      // [8192][3072] bf16
  unsigned short* KATT  = (unsigned short*)(ws + 104857600);     // [8*4][1024][128]
  unsigned short* VT    = (unsigned short*)(ws + 113246208);     // [8*4][128][1024]
  unsigned short* QATT  = XBF;  // alias: x_bf16 dead after GEMM1
  unsigned short* Y     = QKV;  // alias: qkv dead after rope+vtpose

  dim3 tb(32, 8);
  cvt_bf16_kernel<<<16384, 256, 0, stream>>>(x, XBF);
  tpose_f32_bf16<<<dim3(64, 64), tb, 0, stream>>>(wq, WCATT, 2048, 2048);
  tpose_f32_bf16<<<dim3(16, 64), tb, 0, stream>>>(wk, WCATT + (size_t)2048 * 2048, 512, 2048);
  tpose_f32_bf16<<<dim3(16, 64), tb, 0, stream>>>(wv, WCATT + (size_t)2560 * 2048, 512, 2048);
  tpose_f32_bf16<<<dim3(64, 64), tb, 0, stream>>>(wo, WOT, 2048, 2048);
  gemm_v2<0><<<dim3(24, 32), 512, 0, stream>>>(XBF, WCATT, QKV, 3072);
  rope_kernel<<<8192, 256, 0, stream>>>(QKV, sinp, cosp, QATT, KATT);
  vtpose<<<dim3(16, 32, 8), tb, 0, stream>>>(QKV, VT);
  attn_kernel<<<dim3(4, 128), 256, 0, stream>>>(QATT, KATT, VT, Y);
  gemm_v2<1><<<dim3(16, 32), 512, 0, stream>>>(Y, WOT, d_out, 2048);
}